// Round 16
// baseline (194.319 us; speedup 1.0000x reference)
//
#include <hip/hip_runtime.h>
#include <hip/hip_bf16.h>
#include <hip/hip_cooperative_groups.h>

namespace cg = cooperative_groups;

typedef __attribute__((ext_vector_type(8))) short short8;
typedef __attribute__((ext_vector_type(4))) float f32x4;
typedef __attribute__((ext_vector_type(2))) float f32x2;

#define BKS      6      // log2 nodes per bucket
#define BKN      64     // nodes per bucket
#define NBMAX    1024   // max buckets (N <= 65536)
#define CAPB_MAX 3072   // max edges per bucket (mean ~1023, huge margin)
#define EPC      2048   // edges per bin chunk (coop path)
#define EPB      4096   // edges per bin block (fallback path)

__device__ __forceinline__ unsigned short f2bf(float f) {
    unsigned u = __builtin_bit_cast(unsigned, f);
    u += 0x7fffu + ((u >> 16) & 1u);
    return (unsigned short)(u >> 16);
}

// ===========================================================================
// COOPERATIVE single-kernel path.
// phase 0: zero gcur/ticket; x -> fp8 xq; W -> Wp fragment-pack.
// phase 1: bin edges by dst>>BKS (LDS histogram + 1 atomic/(chunk,bucket)).
// phase 2: dynamic-ticket bucket loop: in-LDS CSR + quarter-owns-node fp8
//          gather + fused GEMM+ReLU (A x-half converted inline from f32 x).
// ===========================================================================
__global__ __launch_bounds__(512, 4) void coop_kernel(
    const float* __restrict__ x, unsigned char* __restrict__ xq,
    const float* __restrict__ W, unsigned short* __restrict__ Wp,
    const int* __restrict__ src, const int* __restrict__ dst,
    unsigned* gcur, unsigned* __restrict__ gbuf, unsigned* ticket,
    float* __restrict__ out, int N, int E, int nb, int capb, int nx8)
{
    cg::grid_group grid = cg::this_grid();

    __shared__ unsigned h_cnt[NBMAX];
    __shared__ unsigned h_base[NBMAX];
    __shared__ unsigned cntA[BKN];
    __shared__ unsigned degs[BKN];
    __shared__ unsigned curA[BKN];
    __shared__ unsigned elist[CAPB_MAX];
    __shared__ unsigned short aggs[BKN][136];
    __shared__ unsigned tkt;

    int tid  = threadIdx.x;
    int gid  = blockIdx.x * 512 + tid;
    int gstr = gridDim.x * 512;

    // ---- phase 0 ----
    for (int i = gid; i < nx8; i += gstr) {
        const float4* p = (const float4*)(x + (size_t)i * 8);
        float4 lo = p[0], hi = p[1];
        int p0 = 0, p1 = 0;
        p0 = __builtin_amdgcn_cvt_pk_fp8_f32(lo.x, lo.y, p0, false);
        p0 = __builtin_amdgcn_cvt_pk_fp8_f32(lo.z, lo.w, p0, true);
        p1 = __builtin_amdgcn_cvt_pk_fp8_f32(hi.x, hi.y, p1, false);
        p1 = __builtin_amdgcn_cvt_pk_fp8_f32(hi.z, hi.w, p1, true);
        uint2 q; q.x = (unsigned)p0; q.y = (unsigned)p1;
        *(uint2*)(xq + (size_t)i * 8) = q;
    }
    if (gid < 4096) {   // W -> Wp fragment order (1 KB wave B-loads)
        const float4* p = (const float4*)(W + (size_t)gid * 8);
        float4 lo = p[0], hi = p[1];
        short8 v;
        v[0] = (short)f2bf(lo.x); v[1] = (short)f2bf(lo.y);
        v[2] = (short)f2bf(lo.z); v[3] = (short)f2bf(lo.w);
        v[4] = (short)f2bf(hi.x); v[5] = (short)f2bf(hi.y);
        v[6] = (short)f2bf(hi.z); v[7] = (short)f2bf(hi.w);
        int r    = gid >> 5;
        int c0   = (gid & 31) << 3;
        int ct   = r >> 4;
        int arow = r & 15;
        int ks   = c0 >> 5;
        int kgrp = (c0 >> 3) & 3;
        int l    = arow | (kgrp << 4);
        *(short8*)(Wp + (((size_t)(ct * 8 + ks) * 64 + l) * 8)) = v;
    }
    for (int i = gid; i < nb; i += gstr) gcur[i] = 0u;
    if (gid == 0) *ticket = 0u;

    grid.sync();

    // ---- phase 1: bin (chunks of EPC edges) ----
    int nchunks = (E + EPC - 1) / EPC;
    for (int ch = blockIdx.x; ch < nchunks; ch += gridDim.x) {
        for (int t = tid; t < nb; t += 512) h_cnt[t] = 0u;
        __syncthreads();
        int e0 = ch * EPC + tid;
        unsigned pk[EPC / 512];
        unsigned short bk[EPC / 512], pp[EPC / 512];
#pragma unroll
        for (int it = 0; it < EPC / 512; ++it) {
            int e = e0 + it * 512;
            bk[it] = 0xFFFFu;
            if (e < E) {
                int d = dst[e];
                unsigned b = (unsigned)d >> BKS;
                pk[it] = (unsigned)src[e] | ((unsigned)(d & (BKN - 1)) << 24);
                pp[it] = (unsigned short)atomicAdd(&h_cnt[b], 1u);
                bk[it] = (unsigned short)b;
            }
        }
        __syncthreads();
        for (int t = tid; t < nb; t += 512)
            h_base[t] = h_cnt[t] ? atomicAdd(&gcur[t], h_cnt[t]) : 0u;
        __syncthreads();
#pragma unroll
        for (int it = 0; it < EPC / 512; ++it) {
            if (bk[it] != 0xFFFFu) {
                unsigned b = bk[it];
                unsigned off = h_base[b] + pp[it];
                if (off < (unsigned)capb) gbuf[(size_t)b * capb + off] = pk[it];
            }
        }
        __syncthreads();
    }

    grid.sync();

    // ---- phase 2: dynamic-ticket bucket loop ----
    int wv = tid >> 6, l = tid & 63;
    int q4 = l >> 4, ql = l & 15;

    while (true) {
        __syncthreads();
        if (tid == 0) tkt = atomicAdd(ticket, 1u);
        __syncthreads();
        unsigned b = tkt;
        if (b >= (unsigned)nb) break;

        unsigned cntB = gcur[b];
        if (cntB > (unsigned)capb) cntB = (unsigned)capb;
        const unsigned* bb = gbuf + (size_t)b * capb;
        int base = (int)b << BKS;

        // -- stage A: in-LDS CSR --
        if (tid < BKN) cntA[tid] = 0u;
        __syncthreads();
        for (unsigned i = tid; i < cntB; i += 512)
            atomicAdd(&cntA[bb[i] >> 24], 1u);
        __syncthreads();
        if (tid < BKN) degs[tid] = cntA[tid];
        __syncthreads();
#pragma unroll
        for (int off = 1; off < BKN; off <<= 1) {
            unsigned t = (tid < BKN && tid >= off) ? cntA[tid - off] : 0u;
            __syncthreads();
            if (tid < BKN) cntA[tid] += t;
            __syncthreads();
        }
        if (tid < BKN) curA[tid] = cntA[tid] - degs[tid];
        __syncthreads();
        for (unsigned i = tid; i < cntB; i += 512) {
            unsigned pk = bb[i];
            unsigned p  = atomicAdd(&curA[pk >> 24], 1u);
            elist[p] = pk & 0x00FFFFFFu;
        }
        __syncthreads();

        // -- stage B: quarter-owns-node fp8 gather -> LDS bf16 mean --
#pragma unroll
        for (int pass = 0; pass < BKN / 32; ++pass) {
            int r0 = pass * 32 + wv * 4 + q4;
            unsigned endi  = cntA[r0];
            unsigned dg    = degs[r0];
            unsigned start = endi - dg;
            float acc[8] = {0.f, 0.f, 0.f, 0.f, 0.f, 0.f, 0.f, 0.f};

            for (unsigned eb = start; eb < endi; eb += 4) {
                unsigned last = endi - 1;
                unsigned e1 = eb + 1, e2 = eb + 2, e3 = eb + 3;
                float w0 = 1.0f;
                float w1 = (e1 < endi) ? 1.0f : 0.0f;
                float w2 = (e2 < endi) ? 1.0f : 0.0f;
                float w3 = (e3 < endi) ? 1.0f : 0.0f;
                unsigned i1 = (e1 < endi) ? e1 : last;
                unsigned i2 = (e2 < endi) ? e2 : last;
                unsigned i3 = (e3 < endi) ? e3 : last;
                unsigned s0 = elist[eb], s1 = elist[i1];
                unsigned s2 = elist[i2], s3 = elist[i3];
                uint2 u0 = *(const uint2*)(xq + (size_t)s0 * 128 + ql * 8);
                uint2 u1 = *(const uint2*)(xq + (size_t)s1 * 128 + ql * 8);
                uint2 u2 = *(const uint2*)(xq + (size_t)s2 * 128 + ql * 8);
                uint2 u3 = *(const uint2*)(xq + (size_t)s3 * 128 + ql * 8);
#define ACC8(u, w)                                                            \
                {                                                             \
                    f32x2 a0 = __builtin_amdgcn_cvt_pk_f32_fp8((int)(u).x, false);\
                    f32x2 a1 = __builtin_amdgcn_cvt_pk_f32_fp8((int)(u).x, true); \
                    f32x2 a2 = __builtin_amdgcn_cvt_pk_f32_fp8((int)(u).y, false);\
                    f32x2 a3 = __builtin_amdgcn_cvt_pk_f32_fp8((int)(u).y, true); \
                    acc[0] = fmaf(w, a0.x, acc[0]); acc[1] = fmaf(w, a0.y, acc[1]);\
                    acc[2] = fmaf(w, a1.x, acc[2]); acc[3] = fmaf(w, a1.y, acc[3]);\
                    acc[4] = fmaf(w, a2.x, acc[4]); acc[5] = fmaf(w, a2.y, acc[5]);\
                    acc[6] = fmaf(w, a3.x, acc[6]); acc[7] = fmaf(w, a3.y, acc[7]);\
                }
                ACC8(u0, w0); ACC8(u1, w1); ACC8(u2, w2); ACC8(u3, w3);
#undef ACC8
            }

            float inv = dg ? 1.0f / (float)dg : 1.0f;
            short8 st;
#pragma unroll
            for (int j = 0; j < 8; ++j) st[j] = (short)f2bf(acc[j] * inv);
            *(short8*)&aggs[r0][ql * 8] = st;
        }
        __syncthreads();

        // -- stage C: GEMM + ReLU (A x-half inline from f32 x) --
        int w    = tid >> 6;
        int rt   = w >> 1;
        int cth  = w & 1;
        int arow = l & 15;
        int kgrp = l >> 4;
        int row  = base + rt * 16 + arow;
        bool rok = row < N;

        short8 afrag[8];
#pragma unroll
        for (int ks = 0; ks < 4; ++ks) {
            short8 a = {};
            if (rok) {
                const float4* p = (const float4*)(x + (size_t)row * 128 + ks * 32 + kgrp * 8);
                float4 lo = p[0], hi = p[1];
                a[0] = (short)f2bf(lo.x); a[1] = (short)f2bf(lo.y);
                a[2] = (short)f2bf(lo.z); a[3] = (short)f2bf(lo.w);
                a[4] = (short)f2bf(hi.x); a[5] = (short)f2bf(hi.y);
                a[6] = (short)f2bf(hi.z); a[7] = (short)f2bf(hi.w);
            }
            afrag[ks] = a;
        }
#pragma unroll
        for (int ks = 0; ks < 4; ++ks)
            afrag[4 + ks] = *(const short8*)&aggs[rt * 16 + arow][ks * 32 + kgrp * 8];

        f32x4 acc2[4];
#pragma unroll
        for (int c = 0; c < 4; ++c) acc2[c] = (f32x4){0.f, 0.f, 0.f, 0.f};

#pragma unroll
        for (int ks = 0; ks < 8; ++ks) {
            short8 a = afrag[ks];
#pragma unroll
            for (int c = 0; c < 4; ++c) {
                int ct = cth * 4 + c;
                const short8* bp =
                    (const short8*)(Wp + (((size_t)(ct * 8 + ks) * 64 + l) * 8));
                acc2[c] = __builtin_amdgcn_mfma_f32_16x16x32_bf16(a, *bp, acc2[c], 0, 0, 0);
            }
        }

#pragma unroll
        for (int c = 0; c < 4; ++c) {
#pragma unroll
            for (int r = 0; r < 4; ++r) {
                int orow = base + rt * 16 + kgrp * 4 + r;
                if (orow < N) {
                    out[(size_t)orow * 128 + (cth * 4 + c) * 16 + arow] =
                        fmaxf(acc2[c][r], 0.0f);
                }
            }
        }
    }
}

// ===========================================================================
// FALLBACK path (round-14, proven 66.7 µs): prepbin + agg_gemm.
// ===========================================================================
__global__ __launch_bounds__(256) void prepbin_kernel(
    const float* __restrict__ x, unsigned short* __restrict__ xb,
    unsigned char* __restrict__ xq,
    const float* __restrict__ W, unsigned short* __restrict__ Wp,
    const int* __restrict__ src, const int* __restrict__ dst,
    unsigned* gcur, unsigned* __restrict__ gbuf,
    int E, int nb, int capb, int nx8)
{
    __shared__ unsigned cnt[NBMAX];
    __shared__ unsigned gbase[NBMAX];
    int tid = threadIdx.x;
    int gid = blockIdx.x * 256 + tid;
    int gstr = gridDim.x * 256;

    for (int i = gid; i < nx8; i += gstr) {
        const float4* p = (const float4*)(x + (size_t)i * 8);
        float4 lo = p[0], hi = p[1];
        short8 v;
        v[0] = (short)f2bf(lo.x); v[1] = (short)f2bf(lo.y);
        v[2] = (short)f2bf(lo.z); v[3] = (short)f2bf(lo.w);
        v[4] = (short)f2bf(hi.x); v[5] = (short)f2bf(hi.y);
        v[6] = (short)f2bf(hi.z); v[7] = (short)f2bf(hi.w);
        *(short8*)(xb + (size_t)i * 8) = v;

        int p0 = 0, p1 = 0;
        p0 = __builtin_amdgcn_cvt_pk_fp8_f32(lo.x, lo.y, p0, false);
        p0 = __builtin_amdgcn_cvt_pk_fp8_f32(lo.z, lo.w, p0, true);
        p1 = __builtin_amdgcn_cvt_pk_fp8_f32(hi.x, hi.y, p1, false);
        p1 = __builtin_amdgcn_cvt_pk_fp8_f32(hi.z, hi.w, p1, true);
        uint2 q; q.x = (unsigned)p0; q.y = (unsigned)p1;
        *(uint2*)(xq + (size_t)i * 8) = q;
    }
    if (gid < 4096) {
        const float4* p = (const float4*)(W + (size_t)gid * 8);
        float4 lo = p[0], hi = p[1];
        short8 v;
        v[0] = (short)f2bf(lo.x); v[1] = (short)f2bf(lo.y);
        v[2] = (short)f2bf(lo.z); v[3] = (short)f2bf(lo.w);
        v[4] = (short)f2bf(hi.x); v[5] = (short)f2bf(hi.y);
        v[6] = (short)f2bf(hi.z); v[7] = (short)f2bf(hi.w);
        int r    = gid >> 5;
        int c0   = (gid & 31) << 3;
        int ct   = r >> 4;
        int arow = r & 15;
        int ks   = c0 >> 5;
        int kgrp = (c0 >> 3) & 3;
        int l    = arow | (kgrp << 4);
        *(short8*)(Wp + (((size_t)(ct * 8 + ks) * 64 + l) * 8)) = v;
    }

    int EB = (E + EPB - 1) / EPB;
    if ((int)blockIdx.x < EB) {
        for (int t = tid; t < nb; t += 256) cnt[t] = 0u;
        __syncthreads();
        int e0 = blockIdx.x * EPB + tid;
        unsigned pk[EPB / 256];
        unsigned short bk[EPB / 256], pp[EPB / 256];
#pragma unroll
        for (int it = 0; it < EPB / 256; ++it) {
            int e = e0 + it * 256;
            bk[it] = 0xFFFFu;
            if (e < E) {
                int d = dst[e];
                unsigned b = (unsigned)d >> BKS;
                pk[it] = (unsigned)src[e] | ((unsigned)(d & (BKN - 1)) << 24);
                pp[it] = (unsigned short)atomicAdd(&cnt[b], 1u);
                bk[it] = (unsigned short)b;
            }
        }
        __syncthreads();
        for (int t = tid; t < nb; t += 256)
            gbase[t] = cnt[t] ? atomicAdd(&gcur[t], cnt[t]) : 0u;
        __syncthreads();
#pragma unroll
        for (int it = 0; it < EPB / 256; ++it) {
            if (bk[it] != 0xFFFFu) {
                unsigned b = bk[it];
                unsigned off = gbase[b] + pp[it];
                if (off < (unsigned)capb) gbuf[(size_t)b * capb + off] = pk[it];
            }
        }
    }
}

__global__ __launch_bounds__(512) void agg_gemm_kernel(
    const unsigned short* __restrict__ xb,
    const unsigned char* __restrict__ xq,
    const unsigned* __restrict__ gbuf,
    const unsigned* __restrict__ gcur,
    const unsigned short* __restrict__ Wp,
    float* __restrict__ out, int N, int capb)
{
    __shared__ unsigned cnt[BKN];
    __shared__ unsigned degs[BKN];
    __shared__ unsigned cur[BKN];
    __shared__ unsigned elist[CAPB_MAX];
    __shared__ unsigned short aggs[BKN][136];

    int tid = threadIdx.x;
    int b   = blockIdx.x;
    unsigned cntB = gcur[b];
    if (cntB > (unsigned)capb) cntB = (unsigned)capb;
    const unsigned* bb = gbuf + (size_t)b * capb;

    if (tid < BKN) cnt[tid] = 0u;
    __syncthreads();
    for (unsigned i = tid; i < cntB; i += 512)
        atomicAdd(&cnt[bb[i] >> 24], 1u);
    __syncthreads();
    if (tid < BKN) degs[tid] = cnt[tid];
    __syncthreads();
#pragma unroll
    for (int off = 1; off < BKN; off <<= 1) {
        unsigned t = (tid < BKN && tid >= off) ? cnt[tid - off] : 0u;
        __syncthreads();
        if (tid < BKN) cnt[tid] += t;
        __syncthreads();
    }
    if (tid < BKN) cur[tid] = cnt[tid] - degs[tid];
    __syncthreads();
    for (unsigned i = tid; i < cntB; i += 512) {
        unsigned pk = bb[i];
        unsigned p  = atomicAdd(&cur[pk >> 24], 1u);
        elist[p] = pk & 0x00FFFFFFu;
    }
    __syncthreads();

    int wv = tid >> 6, l = tid & 63;
    int q4 = l >> 4, ql = l & 15;
    int base = b << BKS;

#pragma unroll
    for (int pass = 0; pass < BKN / 32; ++pass) {
        int r0 = pass * 32 + wv * 4 + q4;
        unsigned endi  = cnt[r0];
        unsigned dg    = degs[r0];
        unsigned start = endi - dg;
        float acc[8] = {0.f, 0.f, 0.f, 0.f, 0.f, 0.f, 0.f, 0.f};

        for (unsigned eb = start; eb < endi; eb += 4) {
            unsigned last = endi - 1;
            unsigned e1 = eb + 1, e2 = eb + 2, e3 = eb + 3;
            float w0 = 1.0f;
            float w1 = (e1 < endi) ? 1.0f : 0.0f;
            float w2 = (e2 < endi) ? 1.0f : 0.0f;
            float w3 = (e3 < endi) ? 1.0f : 0.0f;
            unsigned i1 = (e1 < endi) ? e1 : last;
            unsigned i2 = (e2 < endi) ? e2 : last;
            unsigned i3 = (e3 < endi) ? e3 : last;
            unsigned s0 = elist[eb], s1 = elist[i1];
            unsigned s2 = elist[i2], s3 = elist[i3];
            uint2 u0 = *(const uint2*)(xq + (size_t)s0 * 128 + ql * 8);
            uint2 u1 = *(const uint2*)(xq + (size_t)s1 * 128 + ql * 8);
            uint2 u2 = *(const uint2*)(xq + (size_t)s2 * 128 + ql * 8);
            uint2 u3 = *(const uint2*)(xq + (size_t)s3 * 128 + ql * 8);
#define ACC8(u, w)                                                            \
            {                                                                 \
                f32x2 a0 = __builtin_amdgcn_cvt_pk_f32_fp8((int)(u).x, false);\
                f32x2 a1 = __builtin_amdgcn_cvt_pk_f32_fp8((int)(u).x, true); \
                f32x2 a2 = __builtin_amdgcn_cvt_pk_f32_fp8((int)(u).y, false);\
                f32x2 a3 = __builtin_amdgcn_cvt_pk_f32_fp8((int)(u).y, true); \
                acc[0] = fmaf(w, a0.x, acc[0]); acc[1] = fmaf(w, a0.y, acc[1]);\
                acc[2] = fmaf(w, a1.x, acc[2]); acc[3] = fmaf(w, a1.y, acc[3]);\
                acc[4] = fmaf(w, a2.x, acc[4]); acc[5] = fmaf(w, a2.y, acc[5]);\
                acc[6] = fmaf(w, a3.x, acc[6]); acc[7] = fmaf(w, a3.y, acc[7]);\
            }
            ACC8(u0, w0); ACC8(u1, w1); ACC8(u2, w2); ACC8(u3, w3);
#undef ACC8
        }

        float inv = dg ? 1.0f / (float)dg : 1.0f;
        short8 st;
#pragma unroll
        for (int j = 0; j < 8; ++j) st[j] = (short)f2bf(acc[j] * inv);
        *(short8*)&aggs[r0][ql * 8] = st;
    }
    __syncthreads();

    int w    = tid >> 6;
    int rt   = w >> 1;
    int cth  = w & 1;
    int arow = l & 15;
    int kgrp = l >> 4;
    int row  = base + rt * 16 + arow;
    bool rok = row < N;

    short8 afrag[8];
#pragma unroll
    for (int ks = 0; ks < 4; ++ks) {
        short8 a = {};
        if (rok) a = *(const short8*)(xb + (size_t)row * 128 + ks * 32 + kgrp * 8);
        afrag[ks] = a;
    }
#pragma unroll
    for (int ks = 0; ks < 4; ++ks)
        afrag[4 + ks] = *(const short8*)&aggs[rt * 16 + arow][ks * 32 + kgrp * 8];

    f32x4 acc[4];
#pragma unroll
    for (int c = 0; c < 4; ++c) acc[c] = (f32x4){0.f, 0.f, 0.f, 0.f};

#pragma unroll
    for (int ks = 0; ks < 8; ++ks) {
        short8 a = afrag[ks];
#pragma unroll
        for (int c = 0; c < 4; ++c) {
            int ct = cth * 4 + c;
            const short8* bp =
                (const short8*)(Wp + (((size_t)(ct * 8 + ks) * 64 + l) * 8));
            acc[c] = __builtin_amdgcn_mfma_f32_16x16x32_bf16(a, *bp, acc[c], 0, 0, 0);
        }
    }

#pragma unroll
    for (int c = 0; c < 4; ++c) {
#pragma unroll
        for (int r = 0; r < 4; ++r) {
            int orow = base + rt * 16 + kgrp * 4 + r;
            if (orow < N) {
                out[(size_t)orow * 128 + (cth * 4 + c) * 16 + arow] =
                    fmaxf(acc[c][r], 0.0f);
            }
        }
    }
}

// ---------------------------------------------------------------------------
extern "C" void kernel_launch(void* const* d_in, const int* in_sizes, int n_in,
                              void* d_out, int out_size, void* d_ws, size_t ws_size,
                              hipStream_t stream) {
    const float* x  = (const float*)d_in[0];
    const int* src  = (const int*)d_in[1];
    const int* dst  = (const int*)d_in[2];
    const float* W  = (const float*)d_in[4];

    int N = in_sizes[0] / 128;
    int E = in_sizes[1];
    float* out = (float*)d_out;

    int nb = (N + BKN - 1) >> BKS;
    int capb = 2 * (E / (nb > 0 ? nb : 1)) + 1024;
    capb = (capb + 63) & ~63;
    if (capb > CAPB_MAX) capb = CAPB_MAX;

    char* ws = (char*)d_ws;
    size_t o = 0;
    auto carve = [&](size_t bytes) {
        char* p = ws + o;
        o += (bytes + 255) & ~(size_t)255;
        return p;
    };
    unsigned* gcur     = (unsigned*)carve((size_t)nb * 4);
    unsigned* ticket   = (unsigned*)carve(256);
    unsigned* gbuf     = (unsigned*)carve((size_t)nb * capb * 4);
    unsigned short* Wp = (unsigned short*)carve(128 * 256 * 2);
    unsigned short* xb = (unsigned short*)carve((size_t)N * 128 * 2);  // fallback only
    unsigned char* xq  = (unsigned char*)carve((size_t)N * 128);
    (void)ws_size;   // ~30 MB used; harness provides 256 MiB

    int nx8 = N * 16;
    int nblocks = (nb + 1) / 2;            // 391 for nb=782; >=2 blocks/CU co-residency
    if (nblocks < 1) nblocks = 1;

    unsigned char* xq_ = xq;
    unsigned short* Wp_ = Wp;
    unsigned* gcur_ = gcur;
    unsigned* gbuf_ = gbuf;
    unsigned* ticket_ = ticket;
    void* args[] = {(void*)&x, (void*)&xq_, (void*)&W, (void*)&Wp_,
                    (void*)&src, (void*)&dst, (void*)&gcur_, (void*)&gbuf_,
                    (void*)&ticket_, (void*)&out, (void*)&N, (void*)&E,
                    (void*)&nb, (void*)&capb, (void*)&nx8};

    hipError_t err = hipLaunchCooperativeKernel((const void*)coop_kernel,
                                                dim3(nblocks), dim3(512),
                                                args, 0, stream);
    if (err != hipSuccess) {
        // fallback: proven round-14 3-dispatch path
        int EB = (E + EPB - 1) / EPB;
        int CB = (nx8 + 255) / 256;
        int gb = (EB > CB ? EB : CB);
        if (gb < 16) gb = 16;
        hipMemsetAsync(gcur, 0, (size_t)nb * 4, stream);
        prepbin_kernel<<<gb, 256, 0, stream>>>(x, xb, xq, W, Wp, src, dst,
                                               gcur, gbuf, E, nb, capb, nx8);
        agg_gemm_kernel<<<nb, 512, 0, stream>>>(xb, xq, gbuf, gcur, Wp, out, N, capb);
    }
}

// Round 17
// 67.179 us; speedup vs baseline: 2.8926x; 2.8926x over previous
//
#include <hip/hip_runtime.h>
#include <hip/hip_bf16.h>

typedef __attribute__((ext_vector_type(8))) short short8;
typedef __attribute__((ext_vector_type(4))) float f32x4;
typedef __attribute__((ext_vector_type(2))) float f32x2;

#define BKS      6      // log2 nodes per bucket
#define BKN      64     // nodes per bucket
#define ITERA    16     // edges per thread in bin part
#define NBMAX    1024   // max buckets (N <= 65536)
#define CAPB_MAX 3072   // max edges per bucket (mean ~1023, huge margin)

__device__ __forceinline__ unsigned short f2bf(float f) {
    unsigned u = __builtin_bit_cast(unsigned, f);
    u += 0x7fffu + ((u >> 16) & 1u);
    return (unsigned short)(u >> 16);
}

// ---------------------------------------------------------------------------
// K0: prepbin — merged prep + bin (round-14 structure, xb dropped).
// All blocks: x -> fp8 xq (HW cvt); W -> Wp fragment-pack.
// First EB blocks additionally run the bin body. pack = src|(dst&63)<<24.
// ---------------------------------------------------------------------------
__global__ __launch_bounds__(256) void prepbin_kernel(
    const float* __restrict__ x, unsigned char* __restrict__ xq,
    const float* __restrict__ W, unsigned short* __restrict__ Wp,
    const int* __restrict__ src, const int* __restrict__ dst,
    unsigned* gcur, unsigned* __restrict__ gbuf,
    int E, int nb, int capb, int nx8)
{
    __shared__ unsigned cnt[NBMAX];
    __shared__ unsigned gbase[NBMAX];
    int tid = threadIdx.x;
    int gid = blockIdx.x * 256 + tid;
    int gstr = gridDim.x * 256;

    // ---- x -> fp8 ----
    for (int i = gid; i < nx8; i += gstr) {
        const float4* p = (const float4*)(x + (size_t)i * 8);
        float4 lo = p[0], hi = p[1];
        int p0 = 0, p1 = 0;
        p0 = __builtin_amdgcn_cvt_pk_fp8_f32(lo.x, lo.y, p0, false);
        p0 = __builtin_amdgcn_cvt_pk_fp8_f32(lo.z, lo.w, p0, true);
        p1 = __builtin_amdgcn_cvt_pk_fp8_f32(hi.x, hi.y, p1, false);
        p1 = __builtin_amdgcn_cvt_pk_fp8_f32(hi.z, hi.w, p1, true);
        uint2 q; q.x = (unsigned)p0; q.y = (unsigned)p1;
        *(uint2*)(xq + (size_t)i * 8) = q;
    }
    // ---- W -> Wp (fragment order: wave B-load = one 1 KB transaction) ----
    if (gid < 4096) {
        const float4* p = (const float4*)(W + (size_t)gid * 8);
        float4 lo = p[0], hi = p[1];
        short8 v;
        v[0] = (short)f2bf(lo.x); v[1] = (short)f2bf(lo.y);
        v[2] = (short)f2bf(lo.z); v[3] = (short)f2bf(lo.w);
        v[4] = (short)f2bf(hi.x); v[5] = (short)f2bf(hi.y);
        v[6] = (short)f2bf(hi.z); v[7] = (short)f2bf(hi.w);
        int r    = gid >> 5;
        int c0   = (gid & 31) << 3;
        int ct   = r >> 4;
        int arow = r & 15;
        int ks   = c0 >> 5;
        int kgrp = (c0 >> 3) & 3;
        int l    = arow | (kgrp << 4);
        *(short8*)(Wp + (((size_t)(ct * 8 + ks) * 64 + l) * 8)) = v;
    }

    // ---- bin body: first EB blocks only (block-uniform branch) ----
    int EB = (E + 256 * ITERA - 1) / (256 * ITERA);
    if ((int)blockIdx.x < EB) {
        for (int t = tid; t < nb; t += 256) cnt[t] = 0u;
        __syncthreads();

        int e0 = blockIdx.x * (256 * ITERA) + tid;
        unsigned pk[ITERA];
        unsigned short bk[ITERA], pp[ITERA];
#pragma unroll
        for (int it = 0; it < ITERA; ++it) {
            int e = e0 + it * 256;
            bk[it] = 0xFFFFu;
            if (e < E) {
                int d = dst[e];
                unsigned b = (unsigned)d >> BKS;
                pk[it] = (unsigned)src[e] | ((unsigned)(d & (BKN - 1)) << 24);
                pp[it] = (unsigned short)atomicAdd(&cnt[b], 1u);
                bk[it] = (unsigned short)b;
            }
        }
        __syncthreads();
        for (int t = tid; t < nb; t += 256)
            gbase[t] = cnt[t] ? atomicAdd(&gcur[t], cnt[t]) : 0u;
        __syncthreads();
#pragma unroll
        for (int it = 0; it < ITERA; ++it) {
            if (bk[it] != 0xFFFFu) {
                unsigned b = bk[it];
                unsigned off = gbase[b] + pp[it];
                if (off < (unsigned)capb) gbuf[(size_t)b * capb + off] = pk[it];
            }
        }
    }
}

// ---------------------------------------------------------------------------
// K1: agg+gemm fused — one block (512 thr, 8 waves) per 64-node bucket.
// Stage A: in-LDS CSR. Stage B: quarter-owns-node fp8 gather (128 B/row),
// 4-deep clamped, HW cvt decode, f32 accumulate, bf16 LDS mean.
// Stage C: GEMM+ReLU — A x-half converted INLINE from f32 x (xb dropped;
// numerics verified in round 16's coop run), agg-half from LDS, B = Wp.
// ---------------------------------------------------------------------------
__global__ __launch_bounds__(512) void agg_gemm_kernel(
    const float* __restrict__ x,
    const unsigned char* __restrict__ xq,
    const unsigned* __restrict__ gbuf,
    const unsigned* __restrict__ gcur,
    const unsigned short* __restrict__ Wp,
    float* __restrict__ out, int N, int capb)
{
    __shared__ unsigned cnt[BKN];
    __shared__ unsigned degs[BKN];
    __shared__ unsigned cur[BKN];
    __shared__ unsigned elist[CAPB_MAX];
    __shared__ unsigned short aggs[BKN][136];

    int tid = threadIdx.x;
    int b   = blockIdx.x;
    unsigned cntB = gcur[b];
    if (cntB > (unsigned)capb) cntB = (unsigned)capb;
    const unsigned* bb = gbuf + (size_t)b * capb;

    // ---- stage A: in-LDS CSR ----
    if (tid < BKN) cnt[tid] = 0u;
    __syncthreads();
    for (unsigned i = tid; i < cntB; i += 512)
        atomicAdd(&cnt[bb[i] >> 24], 1u);
    __syncthreads();
    if (tid < BKN) degs[tid] = cnt[tid];
    __syncthreads();
#pragma unroll
    for (int off = 1; off < BKN; off <<= 1) {
        unsigned t = (tid < BKN && tid >= off) ? cnt[tid - off] : 0u;
        __syncthreads();
        if (tid < BKN) cnt[tid] += t;
        __syncthreads();
    }
    if (tid < BKN) cur[tid] = cnt[tid] - degs[tid];
    __syncthreads();
    for (unsigned i = tid; i < cntB; i += 512) {
        unsigned pk = bb[i];
        unsigned p  = atomicAdd(&cur[pk >> 24], 1u);
        elist[p] = pk & 0x00FFFFFFu;
    }
    __syncthreads();

    // ---- stage B: quarter-owns-node fp8 gather -> LDS bf16 mean ----
    int wv = tid >> 6, l = tid & 63;
    int q4 = l >> 4, ql = l & 15;
    int base = b << BKS;

#pragma unroll
    for (int pass = 0; pass < BKN / 32; ++pass) {
        int r0 = pass * 32 + wv * 4 + q4;
        unsigned endi  = cnt[r0];
        unsigned dg    = degs[r0];
        unsigned start = endi - dg;
        float acc[8] = {0.f, 0.f, 0.f, 0.f, 0.f, 0.f, 0.f, 0.f};

        for (unsigned eb = start; eb < endi; eb += 4) {
            unsigned last = endi - 1;
            unsigned e1 = eb + 1, e2 = eb + 2, e3 = eb + 3;
            float w0 = 1.0f;
            float w1 = (e1 < endi) ? 1.0f : 0.0f;
            float w2 = (e2 < endi) ? 1.0f : 0.0f;
            float w3 = (e3 < endi) ? 1.0f : 0.0f;
            unsigned i1 = (e1 < endi) ? e1 : last;
            unsigned i2 = (e2 < endi) ? e2 : last;
            unsigned i3 = (e3 < endi) ? e3 : last;
            unsigned s0 = elist[eb], s1 = elist[i1];
            unsigned s2 = elist[i2], s3 = elist[i3];
            uint2 u0 = *(const uint2*)(xq + (size_t)s0 * 128 + ql * 8);
            uint2 u1 = *(const uint2*)(xq + (size_t)s1 * 128 + ql * 8);
            uint2 u2 = *(const uint2*)(xq + (size_t)s2 * 128 + ql * 8);
            uint2 u3 = *(const uint2*)(xq + (size_t)s3 * 128 + ql * 8);
#define ACC8(u, w)                                                            \
            {                                                                 \
                f32x2 a0 = __builtin_amdgcn_cvt_pk_f32_fp8((int)(u).x, false);\
                f32x2 a1 = __builtin_amdgcn_cvt_pk_f32_fp8((int)(u).x, true); \
                f32x2 a2 = __builtin_amdgcn_cvt_pk_f32_fp8((int)(u).y, false);\
                f32x2 a3 = __builtin_amdgcn_cvt_pk_f32_fp8((int)(u).y, true); \
                acc[0] = fmaf(w, a0.x, acc[0]); acc[1] = fmaf(w, a0.y, acc[1]);\
                acc[2] = fmaf(w, a1.x, acc[2]); acc[3] = fmaf(w, a1.y, acc[3]);\
                acc[4] = fmaf(w, a2.x, acc[4]); acc[5] = fmaf(w, a2.y, acc[5]);\
                acc[6] = fmaf(w, a3.x, acc[6]); acc[7] = fmaf(w, a3.y, acc[7]);\
            }
            ACC8(u0, w0); ACC8(u1, w1); ACC8(u2, w2); ACC8(u3, w3);
#undef ACC8
        }

        float inv = dg ? 1.0f / (float)dg : 1.0f;
        short8 st;
#pragma unroll
        for (int j = 0; j < 8; ++j) st[j] = (short)f2bf(acc[j] * inv);
        *(short8*)&aggs[r0][ql * 8] = st;
    }
    __syncthreads();

    // ---- stage C: GEMM + ReLU for this bucket's 64 rows ----
    int w    = tid >> 6;
    int rt   = w >> 1;
    int cth  = w & 1;
    int arow = l & 15;
    int kgrp = l >> 4;
    int row  = base + rt * 16 + arow;
    bool rok = row < N;

    short8 afrag[8];
#pragma unroll
    for (int ks = 0; ks < 4; ++ks) {               // x half: inline f32 -> bf16
        short8 a = {};
        if (rok) {
            const float4* p = (const float4*)(x + (size_t)row * 128 + ks * 32 + kgrp * 8);
            float4 lo = p[0], hi = p[1];
            a[0] = (short)f2bf(lo.x); a[1] = (short)f2bf(lo.y);
            a[2] = (short)f2bf(lo.z); a[3] = (short)f2bf(lo.w);
            a[4] = (short)f2bf(hi.x); a[5] = (short)f2bf(hi.y);
            a[6] = (short)f2bf(hi.z); a[7] = (short)f2bf(hi.w);
        }
        afrag[ks] = a;
    }
#pragma unroll
    for (int ks = 0; ks < 4; ++ks)
        afrag[4 + ks] = *(const short8*)&aggs[rt * 16 + arow][ks * 32 + kgrp * 8];

    f32x4 acc[4];
#pragma unroll
    for (int c = 0; c < 4; ++c) acc[c] = (f32x4){0.f, 0.f, 0.f, 0.f};

#pragma unroll
    for (int ks = 0; ks < 8; ++ks) {
        short8 a = afrag[ks];
#pragma unroll
        for (int c = 0; c < 4; ++c) {
            int ct = cth * 4 + c;
            const short8* bp =
                (const short8*)(Wp + (((size_t)(ct * 8 + ks) * 64 + l) * 8));
            acc[c] = __builtin_amdgcn_mfma_f32_16x16x32_bf16(a, *bp, acc[c], 0, 0, 0);
        }
    }

#pragma unroll
    for (int c = 0; c < 4; ++c) {
#pragma unroll
        for (int r = 0; r < 4; ++r) {
            int orow = base + rt * 16 + kgrp * 4 + r;
            if (orow < N) {
                out[(size_t)orow * 128 + (cth * 4 + c) * 16 + arow] =
                    fmaxf(acc[c][r], 0.0f);
            }
        }
    }
}

// ---------------------------------------------------------------------------
extern "C" void kernel_launch(void* const* d_in, const int* in_sizes, int n_in,
                              void* d_out, int out_size, void* d_ws, size_t ws_size,
                              hipStream_t stream) {
    const float* x  = (const float*)d_in[0];
    const int* src  = (const int*)d_in[1];
    const int* dst  = (const int*)d_in[2];
    const float* W  = (const float*)d_in[4];

    int N = in_sizes[0] / 128;
    int E = in_sizes[1];
    float* out = (float*)d_out;

    int nb = (N + BKN - 1) >> BKS;
    int capb = 2 * (E / (nb > 0 ? nb : 1)) + 1024;
    capb = (capb + 63) & ~63;
    if (capb > CAPB_MAX) capb = CAPB_MAX;

    char* ws = (char*)d_ws;
    size_t o = 0;
    auto carve = [&](size_t bytes) {
        char* p = ws + o;
        o += (bytes + 255) & ~(size_t)255;
        return p;
    };
    unsigned* gcur     = (unsigned*)carve((size_t)nb * 4);
    unsigned* gbuf     = (unsigned*)carve((size_t)nb * capb * 4);
    unsigned short* Wp = (unsigned short*)carve(128 * 256 * 2);
    unsigned char* xq  = (unsigned char*)carve((size_t)N * 128);
    (void)ws_size;   // ~16 MB used; harness provides 256 MiB

    int nx8 = N * 16;
    int gb  = (nx8 + 255) / 256;                       // 3125 for N=50000
    int eb  = (E + 256 * ITERA - 1) / (256 * ITERA);   // 196
    if (gb < eb) gb = eb;
    if (gb < 16) gb = 16;                              // cover W pack

    hipMemsetAsync(gcur, 0, (size_t)nb * 4, stream);
    prepbin_kernel<<<gb, 256, 0, stream>>>(x, xq, W, Wp, src, dst, gcur, gbuf,
                                           E, nb, capb, nx8);
    agg_gemm_kernel<<<nb, 512, 0, stream>>>(x, xq, gbuf, gcur, Wp, out, N, capb);
}